// Round 9
// baseline (2177.787 us; speedup 1.0000x reference)
//
#include <hip/hip_runtime.h>

// ---------------------------------------------------------------------------
// LocationPredictor: embed -> biLSTM -> attention x3 -> masked conv x2 -> loss
// B=128 T=256 E=512 HSZ=1024 HD=512 VOCAB=2048 LVOCAB=11 K=6 STEPS=3
// Output d_out = 2 x float32 (loss, acc). Workspace ~98 MB.
// Mega cooperative kernel (512 blocks, 2/CU):
//   blocks 0..255  : biLSTM scan (round-8 proven sync; x gathered from a 2 MB
//                    L2-resident emb16 table via Xs -> no x16 stream)
//   blocks 256..511: landmark path (l0 -> fused patch-gather conv x2),
//                    overlapped under the LSTM; 2 system counter barriers.
// ---------------------------------------------------------------------------

typedef _Float16 f16;
typedef __attribute__((ext_vector_type(8))) _Float16 f16x8;
typedef __attribute__((ext_vector_type(4))) float f32x4;

#define DEV __device__ __forceinline__

DEV void gload_lds16(const void* g, void* lds) {   // cached (L1+L2)
  __builtin_amdgcn_global_load_lds(
      (const __attribute__((address_space(1))) unsigned*)g,
      (__attribute__((address_space(3))) unsigned*)lds, 16, 0, 0);
}
DEV void gload_lds16c(const void* g, void* lds) {  // SC0|SC1: read MALL
  __builtin_amdgcn_global_load_lds(
      (const __attribute__((address_space(1))) unsigned*)g,
      (__attribute__((address_space(3))) unsigned*)lds, 16, 0, 17);
}
DEV float sigm(float x) { return 1.0f / (1.0f + __expf(-x)); }
DEV float tanh_(float x) { return 1.0f - 2.0f / (__expf(2.0f * x) + 1.0f); }
DEV unsigned pck(float a, float b) {
  union { unsigned u; f16 h[2]; } c; c.h[0] = (f16)a; c.h[1] = (f16)b; return c.u;
}

// ---------------------------------------------------------------------------
// Generic f16 GEMM: C[M][N] = A[M][K] * B[N][K]^T (+bias[n]); tiles 128x128,
// BK=32, global_load_lds staging, mfma_f32_16x16x32_f16. cmode 1->f16, 0->f32.
// (post-LSTM controller-update GEMMs only)
// ---------------------------------------------------------------------------
__global__ __launch_bounds__(256) void gemm_kernel(
    const f16* __restrict__ A, const f16* __restrict__ B,
    const float* __restrict__ bias, void* __restrict__ Cp,
    int M, int N, int K, int cmode) {
  __shared__ f16 As[128 * 32];
  __shared__ f16 Bs[128 * 32];
  const int tid = threadIdx.x;
  const int w = tid >> 6, l = tid & 63;
  const int m0 = blockIdx.x * 128, n0 = blockIdx.y * 128;
  const int wm = (w & 1) * 64, wn = (w >> 1) * 64;
  const int lr = l & 15, lq = l >> 4;
  const int srow = w * 32 + (l >> 2);
  const int kc8 = (l & 3) * 8;
  f32x4 acc[4][4];
#pragma unroll
  for (int i = 0; i < 4; ++i)
#pragma unroll
    for (int j = 0; j < 4; ++j) acc[i][j] = (f32x4){0.f, 0.f, 0.f, 0.f};

  for (int kt = 0; kt < K; kt += 32) {
    __syncthreads();
#pragma unroll
    for (int i = 0; i < 2; ++i) {
      gload_lds16(A + (long)(m0 + srow + i * 16) * K + kt + kc8,
                  &As[(w * 32 + i * 16) * 32]);
      gload_lds16(B + (long)(n0 + srow + i * 16) * K + kt + kc8,
                  &Bs[(w * 32 + i * 16) * 32]);
    }
    __syncthreads();
    f16x8 af[4], bf[4];
#pragma unroll
    for (int mi = 0; mi < 4; ++mi)
      af[mi] = *(const f16x8*)&As[(wm + mi * 16 + lr) * 32 + lq * 8];
#pragma unroll
    for (int ni = 0; ni < 4; ++ni)
      bf[ni] = *(const f16x8*)&Bs[(wn + ni * 16 + lr) * 32 + lq * 8];
#pragma unroll
    for (int mi = 0; mi < 4; ++mi)
#pragma unroll
      for (int ni = 0; ni < 4; ++ni)
        acc[mi][ni] =
            __builtin_amdgcn_mfma_f32_16x16x32_f16(af[mi], bf[ni], acc[mi][ni], 0, 0, 0);
  }
#pragma unroll
  for (int mi = 0; mi < 4; ++mi)
#pragma unroll
    for (int ni = 0; ni < 4; ++ni)
#pragma unroll
      for (int r = 0; r < 4; ++r) {
        const int m = m0 + wm + mi * 16 + lq * 4 + r;  // C row = quad*4+reg
        const int n = n0 + wn + ni * 16 + lr;          // C col = lane&15
        float v = acc[mi][ni][r];
        if (bias) v += bias[n];
        if (cmode) ((f16*)Cp)[(long)m * N + n] = (f16)v;
        else       ((float*)Cp)[(long)m * N + n] = v;
      }
}

// ---------------------------------------------------------------------------
// Helper conv tile: C[128x128] at (m0,n0) of  l_dst = patchgather(l_src) @ w4^T
// K=4096 permuted tap-major (k = tap*1024 + ic); A gathered per-lane from
// l_src rows (b*16+nbr(p,tap)) with zero-page for OOB taps.
// ---------------------------------------------------------------------------
DEV void conv_tile(char* smem, int tid, const f16* lsrc, const f16* wsrc,
                   f16* ldst, int m0, int n0, const f16* zbuf) {
  f16* const As = (f16*)smem;             // 8 KB
  f16* const Bs = (f16*)(smem + 8192);    // 8 KB
  const int w = tid >> 6, l = tid & 63;
  const int wm = (w & 1) * 64, wn = (w >> 1) * 64;
  const int lr = l & 15, lq = l >> 4;
  const int srow = w * 32 + (l >> 2);
  const int kc8 = (l & 3) * 8;
  f32x4 acc[4][4];
#pragma unroll
  for (int i = 0; i < 4; ++i)
#pragma unroll
    for (int j = 0; j < 4; ++j) acc[i][j] = (f32x4){0.f, 0.f, 0.f, 0.f};

  for (int kt = 0; kt < 4096; kt += 32) {
    __syncthreads();
    const int k = kt + kc8, tap = k >> 10, ic = k & 1023;
#pragma unroll
    for (int i = 0; i < 2; ++i) {
      const int m = m0 + srow + i * 16;
      const int b = m >> 4, p = m & 15, py = p >> 2, px = p & 3;
      const int nb = p + ((tap == 0) ? -4 : (tap == 1) ? -1 : (tap == 2) ? 1 : 4);
      const bool ok = (tap == 0) ? (py > 0) : (tap == 1) ? (px > 0)
                      : (tap == 2) ? (px < 3) : (py < 3);
      const f16* sa = ok ? (lsrc + ((long)(b * 16 + nb) * 1024 + ic)) : zbuf;
      gload_lds16(sa, &As[(w * 32 + i * 16) * 32]);
      gload_lds16(wsrc + (long)(n0 + srow + i * 16) * 4096 + kt + kc8,
                  &Bs[(w * 32 + i * 16) * 32]);
    }
    __syncthreads();
    f16x8 af[4], bf[4];
#pragma unroll
    for (int mi = 0; mi < 4; ++mi)
      af[mi] = *(const f16x8*)&As[(wm + mi * 16 + lr) * 32 + lq * 8];
#pragma unroll
    for (int ni = 0; ni < 4; ++ni)
      bf[ni] = *(const f16x8*)&Bs[(wn + ni * 16 + lr) * 32 + lq * 8];
#pragma unroll
    for (int mi = 0; mi < 4; ++mi)
#pragma unroll
      for (int ni = 0; ni < 4; ++ni)
        acc[mi][ni] =
            __builtin_amdgcn_mfma_f32_16x16x32_f16(af[mi], bf[ni], acc[mi][ni], 0, 0, 0);
  }
#pragma unroll
  for (int mi = 0; mi < 4; ++mi)
#pragma unroll
    for (int ni = 0; ni < 4; ++ni)
#pragma unroll
      for (int r = 0; r < 4; ++r) {
        const int m = m0 + wm + mi * 16 + lq * 4 + r;
        const int n = n0 + wn + ni * 16 + lr;
        ldst[(long)m * 1024 + n] = (f16)acc[mi][ni][r];
      }
}

// system counter barrier for the 256 helper blocks (cnt/gen are line-padded)
DEV void helper_barrier(int* cnt, int* gen, int tid) {
  __syncthreads();
  if (tid == 0) {
    __threadfence();  // release: flush my block's writes to the MALL
    const int a = __hip_atomic_fetch_add(cnt, 1, __ATOMIC_ACQ_REL,
                                         __HIP_MEMORY_SCOPE_SYSTEM);
    if (a == 255) {
      __hip_atomic_store(gen, 1, __ATOMIC_RELEASE, __HIP_MEMORY_SCOPE_SYSTEM);
    } else {
      while (__hip_atomic_load(gen, __ATOMIC_RELAXED,
                               __HIP_MEMORY_SCOPE_SYSTEM) == 0)
        __builtin_amdgcn_s_sleep(8);
    }
    __threadfence();  // acquire: invalidate before reading peers' data
  }
  __syncthreads();
}

// ---------------------------------------------------------------------------
// Mega cooperative kernel: 512 blocks x 256 threads (2 blocks/CU).
// blocks 0..255: biLSTM (round-8 structure; x gathered from emb16 via Xs).
// blocks 256..511: l0 -> barrier -> conv1 -> barrier -> conv2.
// ---------------------------------------------------------------------------
__global__ __launch_bounds__(256, 2) void mega_kernel(
    const int* __restrict__ Xs, const f16* __restrict__ emb16,
    const float* __restrict__ Wih_f, const float* __restrict__ Wih_b,
    const float* __restrict__ Whh_f, const float* __restrict__ Whh_b,
    const float* __restrict__ b_f, const float* __restrict__ b_b,
    f16* __restrict__ hg, f16* __restrict__ hidden, int* __restrict__ bar,
    const int* __restrict__ lm, const float* __restrict__ mapemb,
    f16* __restrict__ l0b, f16* __restrict__ l1b, f16* __restrict__ l2b,
    const f16* __restrict__ w416, const f16* __restrict__ zbuf) {
  __shared__ char smem[57344];
  const int blk = blockIdx.x, tid = threadIdx.x;
  const int w = tid >> 6, l = tid & 63;

  if (blk >= 256) {
    // ===================== helper path: landmark conv ======================
    const int hb = blk - 256;
    // Phase 0: l0b[bp][h] = sum_k mapemb[lm[bp][k]][h]  (8 bp per block)
    for (int j = 0; j < 8; ++j) {
      const int bp = hb * 8 + j;
      const int h = tid * 4;
      float a0 = 0.f, a1 = 0.f, a2 = 0.f, a3 = 0.f;
#pragma unroll
      for (int k = 0; k < 6; ++k) {
        const float* r = mapemb + lm[bp * 6 + k] * 1024 + h;
        a0 += r[0]; a1 += r[1]; a2 += r[2]; a3 += r[3];
      }
      union { uint2 u; f16 hh[4]; } pk;
      pk.hh[0] = (f16)a0; pk.hh[1] = (f16)a1;
      pk.hh[2] = (f16)a2; pk.hh[3] = (f16)a3;
      *(uint2*)&l0b[(long)bp * 1024 + h] = pk.u;
    }
    helper_barrier(&bar[256], &bar[272], tid);
    if (hb < 128)
      conv_tile(smem, tid, l0b, w416, l1b, (hb & 15) * 128, (hb >> 4) * 128, zbuf);
    helper_barrier(&bar[288], &bar[304], tid);
    if (hb < 128)
      conv_tile(smem, tid, l1b, w416, l2b, (hb & 15) * 128, (hb >> 4) * 128, zbuf);
    return;
  }

  // ========================== LSTM path (round-8) ==========================
  f16* const hs = (f16*)smem;                 // 16 KB h stage [kt][m16][kk32]
  f16* const xs0 = (f16*)(smem + 16384);      // 16 KB x ping
  f16* const xs1 = (f16*)(smem + 32768);      // 16 KB x pong
  float* const gbp = (float*)(smem + 49152);  // 8 KB gate transpose
  const int d = blk >> 7, rr = blk & 127;
  const int ug = rr & 15, bg = rr >> 4;
  const int b0 = bg * 16;
  const int lr = l & 15, lq = l >> 4;
  const int u0 = ug * 32 + w * 8;             // wave-owned unit base
  const float* const Wih = d ? Wih_b : Wih_f;
  const float* const Whh = d ? Whh_b : Whh_f;
  const float* const bb = d ? b_b : b_f;
  int* const flagbase = &bar[((d << 3) + bg) << 4];

  // one-time: weights -> registers as MFMA B-fragments (f32 -> f16)
  f16x8 wih[16][2], whh[16][2];
#pragma unroll
  for (int kt = 0; kt < 16; ++kt)
#pragma unroll
    for (int nt = 0; nt < 2; ++nt) {
      const int n = nt * 16 + lr;                       // gate row within 32
      const long row = (long)((n >> 3) * 512 + u0 + (n & 7));
      const float* pi = Wih + row * 512 + kt * 32 + lq * 8;
      const float* ph = Whh + row * 512 + kt * 32 + lq * 8;
      f16x8 va, vb;
#pragma unroll
      for (int j = 0; j < 8; ++j) { va[j] = (f16)pi[j]; vb[j] = (f16)ph[j]; }
      wih[kt][nt] = va; whh[kt][nt] = vb;
    }
  const int bl = l >> 2, jp = (l & 3) * 2;   // eltwise: row bl, units jp,jp+1
  const int b_my = b0 + bl;
  const float bi0 = bb[u0 + jp],        bi1 = bb[u0 + jp + 1];
  const float bF0 = bb[512 + u0 + jp],  bF1 = bb[512 + u0 + jp + 1];
  const float bg0 = bb[1024 + u0 + jp], bg1 = bb[1024 + u0 + jp + 1];
  const float bo0 = bb[1536 + u0 + jp], bo1 = bb[1536 + u0 + jp + 1];
  float c0 = 0.f, c1 = 0.f;
  f16* const hbase = hg + (d * 2) * 65536;

  // stage h (16 rows x 512 f16), wave w does kt = w*4..w*4+4
#define STAGEH(SRCP)                                                          \
  {                                                                           \
    const f16* _s = (SRCP);                                                   \
    _Pragma("unroll") for (int k4 = 0; k4 < 4; ++k4) {                        \
      const int kt = w * 4 + k4;                                              \
      gload_lds16c(_s + (long)(l >> 2) * 512 + kt * 32 + (l & 3) * 8,         \
                   &hs[(kt * 16) * 32]);                                      \
    }                                                                         \
  }
  // gather-stage x@TP from emb16 via Xs (per-lane source row)
#define STAGEX(DSTP, TP)                                                      \
  {                                                                           \
    const int _xr = Xs[(b0 + (l >> 2)) * 256 + (TP)];                         \
    const f16* _s = emb16 + (long)_xr * 512 + (l & 3) * 8;                    \
    _Pragma("unroll") for (int k4 = 0; k4 < 4; ++k4) {                        \
      const int kt = w * 4 + k4;                                              \
      gload_lds16(_s + kt * 32, &(DSTP)[(kt * 16) * 32]);                     \
    }                                                                         \
  }

  // pre-loop: stage x@t0 -> xs0; x-MFMA@t0; prefetch x@t1 -> xs1
  STAGEX(xs0, d ? 255 : 0);
  __builtin_amdgcn_s_waitcnt(0x0F70);  // vmcnt(0)
  __syncthreads();
  f32x4 a0 = (f32x4){0.f, 0.f, 0.f, 0.f}, a1 = (f32x4){0.f, 0.f, 0.f, 0.f};
#pragma unroll
  for (int kt = 0; kt < 16; ++kt) {
    const f16x8 av = *(const f16x8*)&xs0[(kt * 16 + lr) * 32 + lq * 8];
    a0 = __builtin_amdgcn_mfma_f32_16x16x32_f16(av, wih[kt][0], a0, 0, 0, 0);
    a1 = __builtin_amdgcn_mfma_f32_16x16x32_f16(av, wih[kt][1], a1, 0, 0, 0);
  }
  STAGEX(xs1, d ? 254 : 1);

  for (int s = 0; s < 256; ++s) {
    const int t = d ? (255 - s) : s;
    const f16* const hrd = hbase + (s & 1) * 65536;
    f16* const hwr = hbase + ((s + 1) & 1) * 65536;
    // 1. wait for h@s from the 16 writer blocks of my (d,bg)
    if (w == 0 && l < 16) {
      while (__hip_atomic_load(&flagbase[l], __ATOMIC_RELAXED,
                               __HIP_MEMORY_SCOPE_SYSTEM) < s)
        __builtin_amdgcn_s_sleep(1);
    }
    __syncthreads();
    // 2. stage h@s (coherent, from MALL)
    STAGEH(hrd + (long)b0 * 512);
    __builtin_amdgcn_s_waitcnt(0x0F70);  // vmcnt(0): hs + last x prefetch
    __syncthreads();                     // all waves' chunks landed
    // 3. h-MFMA on top of the x contribution computed in the previous tail
#pragma unroll
    for (int kt = 0; kt < 16; ++kt) {
      const f16x8 av = *(const f16x8*)&hs[(kt * 16 + lr) * 32 + lq * 8];
      a0 = __builtin_amdgcn_mfma_f32_16x16x32_f16(av, whh[kt][0], a0, 0, 0, 0);
      a1 = __builtin_amdgcn_mfma_f32_16x16x32_f16(av, whh[kt][1], a1, 0, 0, 0);
    }
    // 4. wave-local gate transpose + eltwise
#pragma unroll
    for (int r = 0; r < 4; ++r) {
      gbp[(w * 16 + lq * 4 + r) * 32 + lr] = a0[r];
      gbp[(w * 16 + lq * 4 + r) * 32 + 16 + lr] = a1[r];
    }
    __builtin_amdgcn_s_waitcnt(0xC07F);  // lgkmcnt(0): my LDS writes visible
    unsigned hp;
    {
      const float* const gr = &gbp[(w * 16 + bl) * 32];
      float gi = gr[jp] + bi0, gf = gr[8 + jp] + bF0;
      float gg = gr[16 + jp] + bg0, go = gr[24 + jp] + bo0;
      c0 = sigm(gf) * c0 + sigm(gi) * tanh_(gg);
      const float h0 = sigm(go) * tanh_(c0);
      gi = gr[jp + 1] + bi1; gf = gr[8 + jp + 1] + bF1;
      gg = gr[16 + jp + 1] + bg1; go = gr[24 + jp + 1] + bo1;
      c1 = sigm(gf) * c1 + sigm(gi) * tanh_(gg);
      const float h1 = sigm(go) * tanh_(c1);
      hp = pck(h0, h1);
      // h exchange: write-through to the coherence point (round-5 proven)
      __hip_atomic_store((unsigned*)&hwr[(b_my << 9) + u0 + jp], hp,
                         __ATOMIC_RELAXED, __HIP_MEMORY_SCOPE_SYSTEM);
    }
    // 5. drain h stores, block-complete, publish flag
    __builtin_amdgcn_s_waitcnt(0x0F70);  // vmcnt(0)
    __syncthreads();
    if (tid == 0)
      __hip_atomic_store(&flagbase[ug], s + 1, __ATOMIC_RELAXED,
                         __HIP_MEMORY_SCOPE_SYSTEM);
    // 6. tail (hidden store, next x-MFMA, next prefetch) behind the publish
    *(unsigned*)&hidden[((long)b_my * 256 + t) * 1024 + (d << 9) + u0 + jp] = hp;
    if (s < 255) {
      a0 = (f32x4){0.f, 0.f, 0.f, 0.f}; a1 = (f32x4){0.f, 0.f, 0.f, 0.f};
      const f16* const xr = ((s + 1) & 1) ? xs1 : xs0;
#pragma unroll
      for (int kt = 0; kt < 16; ++kt) {
        const f16x8 av = *(const f16x8*)&xr[(kt * 16 + lr) * 32 + lq * 8];
        a0 = __builtin_amdgcn_mfma_f32_16x16x32_f16(av, wih[kt][0], a0, 0, 0, 0);
        a1 = __builtin_amdgcn_mfma_f32_16x16x32_f16(av, wih[kt][1], a1, 0, 0, 0);
      }
      if (s < 254) {
        f16* const xd = (s & 1) ? xs1 : xs0;
        STAGEX(xd, d ? (253 - s) : (s + 2));
      }
    }
  }
#undef STAGEH
#undef STAGEX
}

// ---------------------------------------------------------------------------
// Attention: score = hidden . ctrl, softmax over T, msg = att . hidden.
// ---------------------------------------------------------------------------
__global__ __launch_bounds__(256) void att_kernel(
    const f16* __restrict__ hidden, const float* __restrict__ ctrl,
    const float* __restrict__ seq_mask, float* __restrict__ msg_out,
    f16* __restrict__ cat) {
  __shared__ float sc[256];
  __shared__ float red[4];
  __shared__ float ctl[1024];
  const int b = blockIdx.x, tid = threadIdx.x;
  const int w = tid >> 6, l = tid & 63;
  for (int i = tid; i < 1024; i += 256) ctl[i] = ctrl[b * 1024 + i];
  __syncthreads();
  float cl[16];
#pragma unroll
  for (int j = 0; j < 16; ++j) cl[j] = ctl[l + 64 * j];
  const f16* hb = hidden + (long)b * 262144;
  for (int t = w * 64; t < w * 64 + 64; ++t) {
    float s = 0.f;
#pragma unroll
    for (int j = 0; j < 16; ++j) s += (float)hb[t * 1024 + l + 64 * j] * cl[j];
#pragma unroll
    for (int off = 32; off; off >>= 1) s += __shfl_xor(s, off);
    if (l == 0) sc[t] = s;
  }
  __syncthreads();
  const float v = sc[tid] - 1e30f * (1.0f - seq_mask[b * 256 + tid]);
  float m = v;
#pragma unroll
  for (int off = 32; off; off >>= 1) m = fmaxf(m, __shfl_xor(m, off));
  if (l == 0) red[w] = m;
  __syncthreads();
  const float M = fmaxf(fmaxf(red[0], red[1]), fmaxf(red[2], red[3]));
  const float e = __expf(v - M);
  float ss = e;
#pragma unroll
  for (int off = 32; off; off >>= 1) ss += __shfl_xor(ss, off);
  __syncthreads();
  if (l == 0) red[w] = ss;
  __syncthreads();
  const float S = red[0] + red[1] + red[2] + red[3];
  sc[tid] = e / S;
  __syncthreads();
  const int hc = tid * 4;
  float a0 = 0.f, a1 = 0.f, a2 = 0.f, a3 = 0.f;
  for (int t = 0; t < 256; ++t) {
    const float at = sc[t];
    union { uint2 u; f16 h[4]; } q;
    q.u = *(const uint2*)&hb[t * 1024 + hc];
    a0 += at * (float)q.h[0]; a1 += at * (float)q.h[1];
    a2 += at * (float)q.h[2]; a3 += at * (float)q.h[3];
  }
  float* mo = msg_out + b * 1024 + hc;
  mo[0] = a0; mo[1] = a1; mo[2] = a2; mo[3] = a3;
  if (cat) {
    f16* cm = cat + (long)b * 2048 + hc;
    cm[0] = (f16)a0; cm[1] = (f16)a1; cm[2] = (f16)a2; cm[3] = (f16)a3;
    f16* cc = cat + (long)b * 2048 + 1024 + hc;
    cc[0] = (f16)ctl[hc]; cc[1] = (f16)ctl[hc + 1];
    cc[2] = (f16)ctl[hc + 2]; cc[3] = (f16)ctl[hc + 3];
  }
}

// logits -> softmax -> log_softmax(prob) -> loss/acc (atomicAdd into la[2] f32)
__global__ __launch_bounds__(256) void logits_kernel(
    const f16* __restrict__ l0, const f16* __restrict__ l1, const f16* __restrict__ l2,
    const float* __restrict__ msgs, const int* __restrict__ ys, float* __restrict__ la) {
  __shared__ float lg[16];
  const int b = blockIdx.x, tid = threadIdx.x;
  const int p = tid >> 4, q = tid & 15;
  const float* m0 = msgs + b * 1024;
  const float* m1 = msgs + 131072 + b * 1024;
  const float* m2 = msgs + 262144 + b * 1024;
  const long row = (long)(b * 16 + p) * 1024;
  float part = 0.f;
  for (int i = 0; i < 64; ++i) {
    const int h = q + 16 * i;
    part += (float)l0[row + h] * m0[h] + (float)l1[row + h] * m1[h] +
            (float)l2[row + h] * m2[h];
  }
#pragma unroll
  for (int off = 8; off; off >>= 1) part += __shfl_xor(part, off, 16);
  if (q == 0) lg[p] = part;
  __syncthreads();
  if (tid == 0) {
    float mx = lg[0];
    for (int i = 1; i < 16; ++i) mx = fmaxf(mx, lg[i]);
    float pr[16]; float s = 0.f;
    for (int i = 0; i < 16; ++i) { pr[i] = __expf(lg[i] - mx); s += pr[i]; }
    for (int i = 0; i < 16; ++i) pr[i] /= s;
    float mx2 = pr[0];
    for (int i = 1; i < 16; ++i) mx2 = fmaxf(mx2, pr[i]);
    float s2 = 0.f;
    for (int i = 0; i < 16; ++i) s2 += __expf(pr[i] - mx2);
    const float lse = mx2 + __logf(s2);
    const int y = ys[b * 2] * 4 + ys[b * 2 + 1];
    const float logp = pr[y] - lse;
    int am = 0; float bv = pr[0];
    for (int i = 1; i < 16; ++i) if (pr[i] > bv) { bv = pr[i]; am = i; }
    atomicAdd(&la[0], -logp * (1.0f / 128.0f));
    atomicAdd(&la[1], (am == y) ? (1.0f / 128.0f) : 0.0f);
  }
}

// d_out is 2 x FLOAT32 (loss, acc)
__global__ void finalize_kernel(const float* __restrict__ la,
                                float* __restrict__ out) {
  if (threadIdx.x == 0) { out[0] = la[0]; out[1] = la[1]; }
}

// weight prep: emb16 f16 [2048][512]; updW16 f16 [1024][2048];
// w416 f16 [1024][4096] tap-major (k = tap*1024 + i), taps (0,1),(1,0),(1,2),(2,1);
// zbuf zero page.
__global__ __launch_bounds__(256) void prep_kernel(
    const float* __restrict__ emb, const float* __restrict__ upd_W,
    const float* __restrict__ conv_w, f16* __restrict__ emb16,
    f16* __restrict__ updW16, f16* __restrict__ w416, f16* __restrict__ zbuf) {
  const int idx = blockIdx.x * 256 + threadIdx.x;  // 0..4194303
  if (idx < 1048576) emb16[idx] = (f16)emb[idx];
  if (idx < 2097152) updW16[idx] = (f16)upd_W[idx];
  {
    const int o = idx >> 12, r = idx & 4095, tp = r >> 10, i = r & 1023;
    w416[idx] = (f16)conv_w[(long)(o * 1024 + i) * 9 + 1 + 2 * tp];
  }
  if (idx < 128) zbuf[idx] = (f16)0.f;
}

// zero h state / flags+counters / loss accum, init ctrl = broadcast(feat_ctrl)
__global__ __launch_bounds__(256) void init_kernel(
    f16* __restrict__ hg, int* __restrict__ bar, float* __restrict__ la,
    float* __restrict__ ctrlA, const float* __restrict__ feat) {
  const int idx = blockIdx.x * 256 + threadIdx.x;  // 0..131071
  ((unsigned*)hg)[idx] = 0u;
  ctrlA[idx] = feat[idx & 1023];
  if (idx < 1024) bar[idx] = 0;
  if (idx < 2) la[idx] = 0.f;
}

__global__ void fail_kernel(float* out, int mb) {
  if (threadIdx.x == 0) { out[0] = 12344.0f; out[1] = (float)mb; }
}

// ---------------------------------------------------------------------------
extern "C" void kernel_launch(void* const* d_in, const int* in_sizes, int n_in,
                              void* d_out, int out_size, void* d_ws, size_t ws_size,
                              hipStream_t stream) {
  (void)in_sizes; (void)n_in; (void)out_size;
  const int*   Xs      = (const int*)d_in[0];
  const float* seqmask = (const float*)d_in[1];
  const int*   lm      = (const int*)d_in[2];
  const int*   ys      = (const int*)d_in[3];
  const float* emb     = (const float*)d_in[4];
  const float* W_ih_f  = (const float*)d_in[5];
  const float* W_hh_f  = (const float*)d_in[6];
  const float* b_f     = (const float*)d_in[7];
  const float* W_ih_b  = (const float*)d_in[8];
  const float* W_hh_b  = (const float*)d_in[9];
  const float* b_b     = (const float*)d_in[10];
  const float* feat    = (const float*)d_in[11];
  const float* upd_W   = (const float*)d_in[12];
  const float* upd_b   = (const float*)d_in[13];
  const float* mapemb  = (const float*)d_in[14];
  const float* conv_w  = (const float*)d_in[15];
  float* out = (float*)d_out;  // 2 x f32 (loss, acc)
  char* ws = (char*)d_ws;
  size_t off = 0;
  auto alloc = [&](size_t bytes) {
    void* p = ws + off; off += (bytes + 255) & ~(size_t)255; return p;
  };
  f16*   hid    = (f16*)alloc(67108864);   // hidden f16 [b][t][1024]
  f16*   emb16  = (f16*)alloc(2097152);    // emb f16 [2048][512]
  f16*   hgb    = (f16*)alloc(524288);     // h state [d][parity][128][512]
  int*   bar    = (int*)alloc(4096);       // lstm flags [0..255] | helper cnt/gen
  float* la     = (float*)alloc(256);      // loss/acc f32 accum
  float* ctrlA  = (float*)alloc(524288);
  float* ctrlB  = (float*)alloc(524288);
  float* msgs   = (float*)alloc(1572864);  // 3 x [128][1024] f32
  f16*   cat    = (f16*)alloc(524288);     // [128][2048] f16
  f16*   l0b    = (f16*)alloc(4194304);    // [b*16+p][1024] f16
  f16*   l1b    = (f16*)alloc(4194304);
  f16*   l2b    = (f16*)alloc(4194304);
  f16*   w416   = (f16*)alloc(8388608);    // [1024][4096] f16 tap-major
  f16*   updW16 = (f16*)alloc(4194304);    // [1024][2048] f16
  f16*   zbuf   = (f16*)alloc(256);        // zero page for OOB conv taps
  if (ws_size < off) {                     // ~98 MB needed
    fail_kernel<<<1, 64, 0, stream>>>(out, (int)(off >> 20));
    return;
  }

  init_kernel<<<512, 256, 0, stream>>>(hgb, bar, la, ctrlA, feat);
  prep_kernel<<<16384, 256, 0, stream>>>(emb, upd_W, conv_w, emb16, updW16,
                                         w416, zbuf);
  {
    void* args[] = {(void*)&Xs, (void*)&emb16,
                    (void*)&W_ih_f, (void*)&W_ih_b,
                    (void*)&W_hh_f, (void*)&W_hh_b, (void*)&b_f, (void*)&b_b,
                    (void*)&hgb, (void*)&hid, (void*)&bar,
                    (void*)&lm, (void*)&mapemb,
                    (void*)&l0b, (void*)&l1b, (void*)&l2b,
                    (void*)&w416, (void*)&zbuf};
    hipLaunchCooperativeKernel((void*)mega_kernel, dim3(512), dim3(256), args, 0, stream);
  }
  // attention x3 (controller ping-pong); ctrl' = cat @ upd_W^T + upd_b (f32)
  att_kernel<<<128, 256, 0, stream>>>(hid, ctrlA, seqmask, msgs, cat);
  gemm_kernel<<<dim3(1, 8), 256, 0, stream>>>(cat, updW16, upd_b, ctrlB,
                                              128, 1024, 2048, 0);
  att_kernel<<<128, 256, 0, stream>>>(hid, ctrlB, seqmask, msgs + 131072, cat);
  gemm_kernel<<<dim3(1, 8), 256, 0, stream>>>(cat, updW16, upd_b, ctrlA,
                                              128, 1024, 2048, 0);
  att_kernel<<<128, 256, 0, stream>>>(hid, ctrlA, seqmask, msgs + 262144, nullptr);
  logits_kernel<<<128, 256, 0, stream>>>(l0b, l1b, l2b, msgs, ys, la);
  finalize_kernel<<<1, 64, 0, stream>>>(la, out);
}

// Round 10
// 1485.916 us; speedup vs baseline: 1.4656x; 1.4656x over previous
//
#include <hip/hip_runtime.h>

// ---------------------------------------------------------------------------
// LocationPredictor: embed -> biLSTM -> attention x3 -> masked conv x2 -> loss
// B=128 T=256 E=512 HSZ=1024 HD=512 VOCAB=2048 LVOCAB=11 K=6 STEPS=3
// Output d_out = 2 x float32 (loss, acc). Workspace ~94 MB.
// Cooperative kernel (256 blocks x 256 thr, 1/CU, 188 VGPR — NO spill):
//   phase 0: l0 landmark-embedding sums
//   phase 1: biLSTM scan (round-8 proven sync; x gathered from 2 MB emb16
//            table via Xs -> no x16 stream)
//   phase 2: grid barrier -> conv1 (256 x 64x128 tiles) -> barrier -> conv2
// ---------------------------------------------------------------------------

typedef _Float16 f16;
typedef __attribute__((ext_vector_type(8))) _Float16 f16x8;
typedef __attribute__((ext_vector_type(4))) float f32x4;

#define DEV __device__ __forceinline__

DEV void gload_lds16(const void* g, void* lds) {   // cached (L1+L2)
  __builtin_amdgcn_global_load_lds(
      (const __attribute__((address_space(1))) unsigned*)g,
      (__attribute__((address_space(3))) unsigned*)lds, 16, 0, 0);
}
DEV void gload_lds16c(const void* g, void* lds) {  // SC0|SC1: read MALL
  __builtin_amdgcn_global_load_lds(
      (const __attribute__((address_space(1))) unsigned*)g,
      (__attribute__((address_space(3))) unsigned*)lds, 16, 0, 17);
}
DEV float sigm(float x) { return 1.0f / (1.0f + __expf(-x)); }
DEV float tanh_(float x) { return 1.0f - 2.0f / (__expf(2.0f * x) + 1.0f); }
DEV unsigned pck(float a, float b) {
  union { unsigned u; f16 h[2]; } c; c.h[0] = (f16)a; c.h[1] = (f16)b; return c.u;
}

// ---------------------------------------------------------------------------
// Generic f16 GEMM (controller updates): C[M][N] = A[M][K]*B[N][K]^T (+bias).
// ---------------------------------------------------------------------------
__global__ __launch_bounds__(256) void gemm_kernel(
    const f16* __restrict__ A, const f16* __restrict__ B,
    const float* __restrict__ bias, void* __restrict__ Cp,
    int M, int N, int K, int cmode) {
  __shared__ f16 As[128 * 32];
  __shared__ f16 Bs[128 * 32];
  const int tid = threadIdx.x;
  const int w = tid >> 6, l = tid & 63;
  const int m0 = blockIdx.x * 128, n0 = blockIdx.y * 128;
  const int wm = (w & 1) * 64, wn = (w >> 1) * 64;
  const int lr = l & 15, lq = l >> 4;
  const int srow = w * 32 + (l >> 2);
  const int kc8 = (l & 3) * 8;
  f32x4 acc[4][4];
#pragma unroll
  for (int i = 0; i < 4; ++i)
#pragma unroll
    for (int j = 0; j < 4; ++j) acc[i][j] = (f32x4){0.f, 0.f, 0.f, 0.f};

  for (int kt = 0; kt < K; kt += 32) {
    __syncthreads();
#pragma unroll
    for (int i = 0; i < 2; ++i) {
      gload_lds16(A + (long)(m0 + srow + i * 16) * K + kt + kc8,
                  &As[(w * 32 + i * 16) * 32]);
      gload_lds16(B + (long)(n0 + srow + i * 16) * K + kt + kc8,
                  &Bs[(w * 32 + i * 16) * 32]);
    }
    __syncthreads();
    f16x8 af[4], bf[4];
#pragma unroll
    for (int mi = 0; mi < 4; ++mi)
      af[mi] = *(const f16x8*)&As[(wm + mi * 16 + lr) * 32 + lq * 8];
#pragma unroll
    for (int ni = 0; ni < 4; ++ni)
      bf[ni] = *(const f16x8*)&Bs[(wn + ni * 16 + lr) * 32 + lq * 8];
#pragma unroll
    for (int mi = 0; mi < 4; ++mi)
#pragma unroll
      for (int ni = 0; ni < 4; ++ni)
        acc[mi][ni] =
            __builtin_amdgcn_mfma_f32_16x16x32_f16(af[mi], bf[ni], acc[mi][ni], 0, 0, 0);
  }
#pragma unroll
  for (int mi = 0; mi < 4; ++mi)
#pragma unroll
    for (int ni = 0; ni < 4; ++ni)
#pragma unroll
      for (int r = 0; r < 4; ++r) {
        const int m = m0 + wm + mi * 16 + lq * 4 + r;  // C row = quad*4+reg
        const int n = n0 + wn + ni * 16 + lr;          // C col = lane&15
        float v = acc[mi][ni][r];
        if (bias) v += bias[n];
        if (cmode) ((f16*)Cp)[(long)m * N + n] = (f16)v;
        else       ((float*)Cp)[(long)m * N + n] = v;
      }
}

// full-grid (256 blocks) barrier: release fence -> counter -> acquire fence
DEV void grid_barrier(int* cnt, int* gen, int tid) {
  __syncthreads();
  if (tid == 0) {
    __threadfence();  // release: my block's stores -> device-visible
    const int a = __hip_atomic_fetch_add(cnt, 1, __ATOMIC_ACQ_REL,
                                         __HIP_MEMORY_SCOPE_SYSTEM);
    if (a == 255) {
      __hip_atomic_store(gen, 1, __ATOMIC_RELEASE, __HIP_MEMORY_SCOPE_SYSTEM);
    } else {
      while (__hip_atomic_load(gen, __ATOMIC_RELAXED,
                               __HIP_MEMORY_SCOPE_SYSTEM) == 0)
        __builtin_amdgcn_s_sleep(8);
    }
    __threadfence();  // acquire: invalidate before reading peers' data
  }
  __syncthreads();
}

// conv 64x128 tile: ldst[m0..+64][n0..+128] = patchgather(lsrc) @ w416^T.
// K=4096 tap-major (k = tap*1024+ic); tap is wave-uniform per K-iter; A rows
// gathered per-lane (p = l>>2) with zero-page for OOB taps.
DEV void conv_tile64(char* smem, int tid, const f16* lsrc, const f16* wsrc,
                     f16* ldst, int m0, int n0, const f16* zbuf) {
  f16* const As = (f16*)smem;             // 64 x 32 f16 = 4 KB
  f16* const Bs = (f16*)(smem + 4096);    // 128 x 32 f16 = 8 KB
  const int w = tid >> 6, l = tid & 63;
  const int wn = w * 32;
  const int lr = l & 15, lq = l >> 4;
  const int kc8 = (l & 3) * 8;
  f32x4 acc[4][2];
#pragma unroll
  for (int i = 0; i < 4; ++i)
#pragma unroll
    for (int j = 0; j < 2; ++j) acc[i][j] = (f32x4){0.f, 0.f, 0.f, 0.f};

  for (int kt = 0; kt < 4096; kt += 32) {
    __syncthreads();
    const int tap = kt >> 10;                  // wave-uniform
    const int ic = (kt & 1023) + kc8;          // per-lane k within tap
    {  // A: one instr per wave, rows m0 + w*16 + (l>>2)
      const int m = m0 + w * 16 + (l >> 2);
      const int b = m >> 4, p = m & 15, py = p >> 2, px = p & 3;
      const int nb = p + ((tap == 0) ? -4 : (tap == 1) ? -1 : (tap == 2) ? 1 : 4);
      const bool ok = (tap == 0) ? (py > 0) : (tap == 1) ? (px > 0)
                      : (tap == 2) ? (px < 3) : (py < 3);
      const f16* sa = ok ? (lsrc + ((long)(b * 16 + nb) * 1024 + ic)) : zbuf;
      gload_lds16(sa, &As[(w * 16) * 32]);
    }
#pragma unroll
    for (int i = 0; i < 2; ++i) {  // B: rows n0 + w*32 + i*16 + (l>>2)
      gload_lds16(wsrc + (long)(n0 + w * 32 + i * 16 + (l >> 2)) * 4096 + kt + kc8,
                  &Bs[(w * 32 + i * 16) * 32]);
    }
    __syncthreads();
    f16x8 af[4], bf[2];
#pragma unroll
    for (int mi = 0; mi < 4; ++mi)
      af[mi] = *(const f16x8*)&As[(mi * 16 + lr) * 32 + lq * 8];
#pragma unroll
    for (int ni = 0; ni < 2; ++ni)
      bf[ni] = *(const f16x8*)&Bs[(wn + ni * 16 + lr) * 32 + lq * 8];
#pragma unroll
    for (int mi = 0; mi < 4; ++mi)
#pragma unroll
      for (int ni = 0; ni < 2; ++ni)
        acc[mi][ni] =
            __builtin_amdgcn_mfma_f32_16x16x32_f16(af[mi], bf[ni], acc[mi][ni], 0, 0, 0);
  }
#pragma unroll
  for (int mi = 0; mi < 4; ++mi)
#pragma unroll
    for (int ni = 0; ni < 2; ++ni)
#pragma unroll
      for (int r = 0; r < 4; ++r) {
        const int m = m0 + mi * 16 + lq * 4 + r;
        const int n = n0 + wn + ni * 16 + lr;
        ldst[(long)m * 1024 + n] = (f16)acc[mi][ni][r];
      }
}

// ---------------------------------------------------------------------------
// Cooperative kernel: 256 blocks x 256 threads (1 block/CU, full VGPRs).
// ---------------------------------------------------------------------------
__global__ __launch_bounds__(256, 1) void lstm_conv_kernel(
    const int* __restrict__ Xs, const f16* __restrict__ emb16,
    const float* __restrict__ Wih_f, const float* __restrict__ Wih_b,
    const float* __restrict__ Whh_f, const float* __restrict__ Whh_b,
    const float* __restrict__ b_f, const float* __restrict__ b_b,
    f16* __restrict__ hg, f16* __restrict__ hidden, int* __restrict__ bar,
    const int* __restrict__ lm, const float* __restrict__ mapemb,
    f16* __restrict__ l0b, f16* __restrict__ l1b, f16* __restrict__ l2b,
    const f16* __restrict__ w416, const f16* __restrict__ zbuf) {
  __shared__ char smem[57344];
  const int blk = blockIdx.x, tid = threadIdx.x;
  const int w = tid >> 6, l = tid & 63;

  // ---- phase 0: l0b[bp][h] = sum_k mapemb[lm[bp][k]][h] (8 bp per block) ---
  for (int j = 0; j < 8; ++j) {
    const int bp = blk * 8 + j;
    const int h = tid * 4;
    float a0 = 0.f, a1 = 0.f, a2 = 0.f, a3 = 0.f;
#pragma unroll
    for (int k = 0; k < 6; ++k) {
      const float* r = mapemb + lm[bp * 6 + k] * 1024 + h;
      a0 += r[0]; a1 += r[1]; a2 += r[2]; a3 += r[3];
    }
    union { uint2 u; f16 hh[4]; } pk;
    pk.hh[0] = (f16)a0; pk.hh[1] = (f16)a1; pk.hh[2] = (f16)a2; pk.hh[3] = (f16)a3;
    *(uint2*)&l0b[(long)bp * 1024 + h] = pk.u;
  }

  // ========================== phase 1: biLSTM scan =========================
  f16* const hs = (f16*)smem;                 // 16 KB h stage [kt][m16][kk32]
  f16* const xs0 = (f16*)(smem + 16384);      // 16 KB x ping
  f16* const xs1 = (f16*)(smem + 32768);      // 16 KB x pong
  float* const gbp = (float*)(smem + 49152);  // 8 KB gate transpose
  const int d = blk >> 7, rr = blk & 127;
  const int ug = rr & 15, bg = rr >> 4;
  const int b0 = bg * 16;
  const int lr = l & 15, lq = l >> 4;
  const int u0 = ug * 32 + w * 8;             // wave-owned unit base
  const float* const Wih = d ? Wih_b : Wih_f;
  const float* const Whh = d ? Whh_b : Whh_f;
  const float* const bb = d ? b_b : b_f;
  int* const flagbase = &bar[((d << 3) + bg) << 4];

  // one-time: weights -> registers as MFMA B-fragments (f32 -> f16)
  f16x8 wih[16][2], whh[16][2];
#pragma unroll
  for (int kt = 0; kt < 16; ++kt)
#pragma unroll
    for (int nt = 0; nt < 2; ++nt) {
      const int n = nt * 16 + lr;                       // gate row within 32
      const long row = (long)((n >> 3) * 512 + u0 + (n & 7));
      const float* pi = Wih + row * 512 + kt * 32 + lq * 8;
      const float* ph = Whh + row * 512 + kt * 32 + lq * 8;
      f16x8 va, vb;
#pragma unroll
      for (int j = 0; j < 8; ++j) { va[j] = (f16)pi[j]; vb[j] = (f16)ph[j]; }
      wih[kt][nt] = va; whh[kt][nt] = vb;
    }
  const int bl = l >> 2, jp = (l & 3) * 2;   // eltwise: row bl, units jp,jp+1
  const int b_my = b0 + bl;
  const float bi0 = bb[u0 + jp],        bi1 = bb[u0 + jp + 1];
  const float bF0 = bb[512 + u0 + jp],  bF1 = bb[512 + u0 + jp + 1];
  const float bg0 = bb[1024 + u0 + jp], bg1 = bb[1024 + u0 + jp + 1];
  const float bo0 = bb[1536 + u0 + jp], bo1 = bb[1536 + u0 + jp + 1];
  float c0 = 0.f, c1 = 0.f;
  f16* const hbase = hg + (d * 2) * 65536;

#define STAGEH(SRCP)                                                          \
  {                                                                           \
    const f16* _s = (SRCP);                                                   \
    _Pragma("unroll") for (int k4 = 0; k4 < 4; ++k4) {                        \
      const int kt = w * 4 + k4;                                              \
      gload_lds16c(_s + (long)(l >> 2) * 512 + kt * 32 + (l & 3) * 8,         \
                   &hs[(kt * 16) * 32]);                                      \
    }                                                                         \
  }
#define STAGEX(DSTP, TP)                                                      \
  {                                                                           \
    const int _xr = Xs[(b0 + (l >> 2)) * 256 + (TP)];                         \
    const f16* _s = emb16 + (long)_xr * 512 + (l & 3) * 8;                    \
    _Pragma("unroll") for (int k4 = 0; k4 < 4; ++k4) {                        \
      const int kt = w * 4 + k4;                                              \
      gload_lds16(_s + kt * 32, &(DSTP)[(kt * 16) * 32]);                     \
    }                                                                         \
  }

  // pre-loop: stage x@t0 -> xs0; x-MFMA@t0; prefetch x@t1 -> xs1
  STAGEX(xs0, d ? 255 : 0);
  __builtin_amdgcn_s_waitcnt(0x0F70);  // vmcnt(0)
  __syncthreads();
  f32x4 a0 = (f32x4){0.f, 0.f, 0.f, 0.f}, a1 = (f32x4){0.f, 0.f, 0.f, 0.f};
#pragma unroll
  for (int kt = 0; kt < 16; ++kt) {
    const f16x8 av = *(const f16x8*)&xs0[(kt * 16 + lr) * 32 + lq * 8];
    a0 = __builtin_amdgcn_mfma_f32_16x16x32_f16(av, wih[kt][0], a0, 0, 0, 0);
    a1 = __builtin_amdgcn_mfma_f32_16x16x32_f16(av, wih[kt][1], a1, 0, 0, 0);
  }
  STAGEX(xs1, d ? 254 : 1);

  for (int s = 0; s < 256; ++s) {
    const int t = d ? (255 - s) : s;
    const f16* const hrd = hbase + (s & 1) * 65536;
    f16* const hwr = hbase + ((s + 1) & 1) * 65536;
    // 1. wait for h@s from the 16 writer blocks of my (d,bg)
    if (w == 0 && l < 16) {
      while (__hip_atomic_load(&flagbase[l], __ATOMIC_RELAXED,
                               __HIP_MEMORY_SCOPE_SYSTEM) < s)
        __builtin_amdgcn_s_sleep(1);
    }
    __syncthreads();
    // 2. stage h@s (coherent, from MALL)
    STAGEH(hrd + (long)b0 * 512);
    __builtin_amdgcn_s_waitcnt(0x0F70);  // vmcnt(0): hs + last x prefetch
    __syncthreads();                     // all waves' chunks landed
    // 3. h-MFMA on top of the x contribution computed in the previous tail
#pragma unroll
    for (int kt = 0; kt < 16; ++kt) {
      const f16x8 av = *(const f16x8*)&hs[(kt * 16 + lr) * 32 + lq * 8];
      a0 = __builtin_amdgcn_mfma_f32_16x16x32_f16(av, whh[kt][0], a0, 0, 0, 0);
      a1 = __builtin_amdgcn_mfma_f32_16x16x32_f16(av, whh[kt][1], a1, 0, 0, 0);
    }
    // 4. wave-local gate transpose + eltwise
#pragma unroll
    for (int r = 0; r < 4; ++r) {
      gbp[(w * 16 + lq * 4 + r) * 32 + lr] = a0[r];
      gbp[(w * 16 + lq * 4 + r) * 32 + 16 + lr] = a1[r];
    }
    __builtin_amdgcn_s_waitcnt(0xC07F);  // lgkmcnt(0): my LDS writes visible
    unsigned hp;
    {
      const float* const gr = &gbp[(w * 16 + bl) * 32];
      float gi = gr[jp] + bi0, gf = gr[8 + jp] + bF0;
      float gg = gr[16 + jp] + bg0, go = gr[24 + jp] + bo0;
      c0 = sigm(gf) * c0 + sigm(gi) * tanh_(gg);
      const float h0 = sigm(go) * tanh_(c0);
      gi = gr[jp + 1] + bi1; gf = gr[8 + jp + 1] + bF1;
      gg = gr[16 + jp + 1] + bg1; go = gr[24 + jp + 1] + bo1;
      c1 = sigm(gf) * c1 + sigm(gi) * tanh_(gg);
      const float h1 = sigm(go) * tanh_(c1);
      hp = pck(h0, h1);
      __hip_atomic_store((unsigned*)&hwr[(b_my << 9) + u0 + jp], hp,
                         __ATOMIC_RELAXED, __HIP_MEMORY_SCOPE_SYSTEM);
    }
    // 5. drain h stores, block-complete, publish flag
    __builtin_amdgcn_s_waitcnt(0x0F70);  // vmcnt(0)
    __syncthreads();
    if (tid == 0)
      __hip_atomic_store(&flagbase[ug], s + 1, __ATOMIC_RELAXED,
                         __HIP_MEMORY_SCOPE_SYSTEM);
    // 6. tail (hidden store, next x-MFMA, next prefetch) behind the publish
    *(unsigned*)&hidden[((long)b_my * 256 + t) * 1024 + (d << 9) + u0 + jp] = hp;
    if (s < 255) {
      a0 = (f32x4){0.f, 0.f, 0.f, 0.f}; a1 = (f32x4){0.f, 0.f, 0.f, 0.f};
      const f16* const xr = ((s + 1) & 1) ? xs1 : xs0;
#pragma unroll
      for (int kt = 0; kt < 16; ++kt) {
        const f16x8 av = *(const f16x8*)&xr[(kt * 16 + lr) * 32 + lq * 8];
        a0 = __builtin_amdgcn_mfma_f32_16x16x32_f16(av, wih[kt][0], a0, 0, 0, 0);
        a1 = __builtin_amdgcn_mfma_f32_16x16x32_f16(av, wih[kt][1], a1, 0, 0, 0);
      }
      if (s < 254) {
        f16* const xd = (s & 1) ? xs1 : xs0;
        STAGEX(xd, d ? (253 - s) : (s + 2));
      }
    }
  }
#undef STAGEH
#undef STAGEX

  // ================== phase 2: landmark conv (after scan) ==================
  const int m0 = (blk >> 3) * 64, n0 = (blk & 7) * 128;
  grid_barrier(&bar[512], &bar[528], tid);
  conv_tile64(smem, tid, l0b, w416, l1b, m0, n0, zbuf);
  grid_barrier(&bar[544], &bar[560], tid);
  conv_tile64(smem, tid, l1b, w416, l2b, m0, n0, zbuf);
}

// ---------------------------------------------------------------------------
// Attention: score = hidden . ctrl, softmax over T, msg = att . hidden.
// ---------------------------------------------------------------------------
__global__ __launch_bounds__(256) void att_kernel(
    const f16* __restrict__ hidden, const float* __restrict__ ctrl,
    const float* __restrict__ seq_mask, float* __restrict__ msg_out,
    f16* __restrict__ cat) {
  __shared__ float sc[256];
  __shared__ float red[4];
  __shared__ float ctl[1024];
  const int b = blockIdx.x, tid = threadIdx.x;
  const int w = tid >> 6, l = tid & 63;
  for (int i = tid; i < 1024; i += 256) ctl[i] = ctrl[b * 1024 + i];
  __syncthreads();
  float cl[16];
#pragma unroll
  for (int j = 0; j < 16; ++j) cl[j] = ctl[l + 64 * j];
  const f16* hb = hidden + (long)b * 262144;
  for (int t = w * 64; t < w * 64 + 64; ++t) {
    float s = 0.f;
#pragma unroll
    for (int j = 0; j < 16; ++j) s += (float)hb[t * 1024 + l + 64 * j] * cl[j];
#pragma unroll
    for (int off = 32; off; off >>= 1) s += __shfl_xor(s, off);
    if (l == 0) sc[t] = s;
  }
  __syncthreads();
  const float v = sc[tid] - 1e30f * (1.0f - seq_mask[b * 256 + tid]);
  float m = v;
#pragma unroll
  for (int off = 32; off; off >>= 1) m = fmaxf(m, __shfl_xor(m, off));
  if (l == 0) red[w] = m;
  __syncthreads();
  const float M = fmaxf(fmaxf(red[0], red[1]), fmaxf(red[2], red[3]));
  const float e = __expf(v - M);
  float ss = e;
#pragma unroll
  for (int off = 32; off; off >>= 1) ss += __shfl_xor(ss, off);
  __syncthreads();
  if (l == 0) red[w] = ss;
  __syncthreads();
  const float S = red[0] + red[1] + red[2] + red[3];
  sc[tid] = e / S;
  __syncthreads();
  const int hc = tid * 4;
  float a0 = 0.f, a1 = 0.f, a2 = 0.f, a3 = 0.f;
  for (int t = 0; t < 256; ++t) {
    const float at = sc[t];
    union { uint2 u; f16 h[4]; } q;
    q.u = *(const uint2*)&hb[t * 1024 + hc];
    a0 += at * (float)q.h[0]; a1 += at * (float)q.h[1];
    a2 += at * (float)q.h[2]; a3 += at * (float)q.h[3];
  }
  float* mo = msg_out + b * 1024 + hc;
  mo[0] = a0; mo[1] = a1; mo[2] = a2; mo[3] = a3;
  if (cat) {
    f16* cm = cat + (long)b * 2048 + hc;
    cm[0] = (f16)a0; cm[1] = (f16)a1; cm[2] = (f16)a2; cm[3] = (f16)a3;
    f16* cc = cat + (long)b * 2048 + 1024 + hc;
    cc[0] = (f16)ctl[hc]; cc[1] = (f16)ctl[hc + 1];
    cc[2] = (f16)ctl[hc + 2]; cc[3] = (f16)ctl[hc + 3];
  }
}

// logits -> softmax -> log_softmax(prob) -> loss/acc (atomicAdd into la[2] f32)
__global__ __launch_bounds__(256) void logits_kernel(
    const f16* __restrict__ l0, const f16* __restrict__ l1, const f16* __restrict__ l2,
    const float* __restrict__ msgs, const int* __restrict__ ys, float* __restrict__ la) {
  __shared__ float lg[16];
  const int b = blockIdx.x, tid = threadIdx.x;
  const int p = tid >> 4, q = tid & 15;
  const float* m0 = msgs + b * 1024;
  const float* m1 = msgs + 131072 + b * 1024;
  const float* m2 = msgs + 262144 + b * 1024;
  const long row = (long)(b * 16 + p) * 1024;
  float part = 0.f;
  for (int i = 0; i < 64; ++i) {
    const int h = q + 16 * i;
    part += (float)l0[row + h] * m0[h] + (float)l1[row + h] * m1[h] +
            (float)l2[row + h] * m2[h];
  }
#pragma unroll
  for (int off = 8; off; off >>= 1) part += __shfl_xor(part, off, 16);
  if (q == 0) lg[p] = part;
  __syncthreads();
  if (tid == 0) {
    float mx = lg[0];
    for (int i = 1; i < 16; ++i) mx = fmaxf(mx, lg[i]);
    float pr[16]; float s = 0.f;
    for (int i = 0; i < 16; ++i) { pr[i] = __expf(lg[i] - mx); s += pr[i]; }
    for (int i = 0; i < 16; ++i) pr[i] /= s;
    float mx2 = pr[0];
    for (int i = 1; i < 16; ++i) mx2 = fmaxf(mx2, pr[i]);
    float s2 = 0.f;
    for (int i = 0; i < 16; ++i) s2 += __expf(pr[i] - mx2);
    const float lse = mx2 + __logf(s2);
    const int y = ys[b * 2] * 4 + ys[b * 2 + 1];
    const float logp = pr[y] - lse;
    int am = 0; float bv = pr[0];
    for (int i = 1; i < 16; ++i) if (pr[i] > bv) { bv = pr[i]; am = i; }
    atomicAdd(&la[0], -logp * (1.0f / 128.0f));
    atomicAdd(&la[1], (am == y) ? (1.0f / 128.0f) : 0.0f);
  }
}

// d_out is 2 x FLOAT32 (loss, acc)
__global__ void finalize_kernel(const float* __restrict__ la,
                                float* __restrict__ out) {
  if (threadIdx.x == 0) { out[0] = la[0]; out[1] = la[1]; }
}

// merged init + weight prep:
// emb16 f16 [2048][512]; updW16 f16 [1024][2048]; w416 f16 [1024][4096]
// tap-major (taps rc (0,1),(1,0),(1,2),(2,1)); zbuf zero page; hgb/bar/la
// zeroed; ctrlA = broadcast(feat_ctrl).
__global__ __launch_bounds__(256) void setup_kernel(
    const float* __restrict__ emb, const float* __restrict__ upd_W,
    const float* __restrict__ conv_w, const float* __restrict__ feat,
    f16* __restrict__ emb16, f16* __restrict__ updW16, f16* __restrict__ w416,
    f16* __restrict__ zbuf, f16* __restrict__ hg, int* __restrict__ bar,
    float* __restrict__ la, float* __restrict__ ctrlA) {
  const int idx = blockIdx.x * 256 + threadIdx.x;  // 0..4194303
  if (idx < 1048576) emb16[idx] = (f16)emb[idx];
  if (idx < 2097152) updW16[idx] = (f16)upd_W[idx];
  {
    const int o = idx >> 12, r = idx & 4095, tp = r >> 10, i = r & 1023;
    w416[idx] = (f16)conv_w[(long)(o * 1024 + i) * 9 + 1 + 2 * tp];
  }
  if (idx < 131072) { ((unsigned*)hg)[idx] = 0u; ctrlA[idx] = feat[idx & 1023]; }
  if (idx < 1024) bar[idx] = 0;
  if (idx < 128) zbuf[idx] = (f16)0.f;
  if (idx < 2) la[idx] = 0.f;
}

__global__ void fail_kernel(float* out, int mb) {
  if (threadIdx.x == 0) { out[0] = 12344.0f; out[1] = (float)mb; }
}

// ---------------------------------------------------------------------------
extern "C" void kernel_launch(void* const* d_in, const int* in_sizes, int n_in,
                              void* d_out, int out_size, void* d_ws, size_t ws_size,
                              hipStream_t stream) {
  (void)in_sizes; (void)n_in; (void)out_size;
  const int*   Xs      = (const int*)d_in[0];
  const float* seqmask = (const float*)d_in[1];
  const int*   lm      = (const int*)d_in[2];
  const int*   ys      = (const int*)d_in[3];
  const float* emb     = (const float*)d_in[4];
  const float* W_ih_f  = (const float*)d_in[5];
  const float* W_hh_f  = (const float*)d_in[6];
  const float* b_f     = (const float*)d_in[7];
  const float* W_ih_b  = (const float*)d_in[8];
  const float* W_hh_b  = (const float*)d_in[9];
  const float* b_b     = (const float*)d_in[10];
  const float* feat    = (const float*)d_in[11];
  const float* upd_W   = (const float*)d_in[12];
  const float* upd_b   = (const float*)d_in[13];
  const float* mapemb  = (const float*)d_in[14];
  const float* conv_w  = (const float*)d_in[15];
  float* out = (float*)d_out;  // 2 x f32 (loss, acc)
  char* ws = (char*)d_ws;
  size_t off = 0;
  auto alloc = [&](size_t bytes) {
    void* p = ws + off; off += (bytes + 255) & ~(size_t)255; return p;
  };
  f16*   hid    = (f16*)alloc(67108864);   // hidden f16 [b][t][1024]
  f16*   emb16  = (f16*)alloc(2097152);    // emb f16 [2048][512]
  f16*   hgb    = (f16*)alloc(524288);     // h state [d][parity][128][512]
  int*   bar    = (int*)alloc(4096);       // lstm flags | grid-barrier cnt/gen
  float* la     = (float*)alloc(256);      // loss/acc f32 accum
  float* ctrlA  = (float*)alloc(524288);
  float* ctrlB  = (float*)alloc(524288);
  float* msgs   = (float*)alloc(1572864);  // 3 x [128][1024] f32
  f16*   cat    = (f16*)alloc(524288);     // [128][2048] f16
  f16*   l0b    = (f16*)alloc(4194304);    // [b*16+p][1024] f16
  f16*   l1b    = (f16*)alloc(4194304);
  f16*   l2b    = (f16*)alloc(4194304);
  f16*   w416   = (f16*)alloc(8388608);    // [1024][4096] f16 tap-major
  f16*   updW16 = (f16*)alloc(4194304);    // [1024][2048] f16
  f16*   zbuf   = (f16*)alloc(256);        // zero page for OOB conv taps
  if (ws_size < off) {                     // ~94 MB needed
    fail_kernel<<<1, 64, 0, stream>>>(out, (int)(off >> 20));
    return;
  }

  setup_kernel<<<16384, 256, 0, stream>>>(emb, upd_W, conv_w, feat, emb16,
                                          updW16, w416, zbuf, hgb, bar, la, ctrlA);
  {
    void* args[] = {(void*)&Xs, (void*)&emb16,
                    (void*)&W_ih_f, (void*)&W_ih_b,
                    (void*)&W_hh_f, (void*)&W_hh_b, (void*)&b_f, (void*)&b_b,
                    (void*)&hgb, (void*)&hid, (void*)&bar,
                    (void*)&lm, (void*)&mapemb,
                    (void*)&l0b, (void*)&l1b, (void*)&l2b,
                    (void*)&w416, (void*)&zbuf};
    hipLaunchCooperativeKernel((void*)lstm_conv_kernel, dim3(256), dim3(256),
                               args, 0, stream);
  }
  // attention x3 (controller ping-pong); ctrl' = cat @ upd_W^T + upd_b (f32)
  att_kernel<<<128, 256, 0, stream>>>(hid, ctrlA, seqmask, msgs, cat);
  gemm_kernel<<<dim3(1, 8), 256, 0, stream>>>(cat, updW16, upd_b, ctrlB,
                                              128, 1024, 2048, 0);
  att_kernel<<<128, 256, 0, stream>>>(hid, ctrlB, seqmask, msgs + 131072, cat);
  gemm_kernel<<<dim3(1, 8), 256, 0, stream>>>(cat, updW16, upd_b, ctrlA,
                                              128, 1024, 2048, 0);
  att_kernel<<<128, 256, 0, stream>>>(hid, ctrlA, seqmask, msgs + 262144, nullptr);
  logits_kernel<<<128, 256, 0, stream>>>(l0b, l1b, l2b, msgs, ys, la);
  finalize_kernel<<<1, 64, 0, stream>>>(la, out);
}

// Round 11
// 1434.985 us; speedup vs baseline: 1.5176x; 1.0355x over previous
//
#include <hip/hip_runtime.h>

// ---------------------------------------------------------------------------
// LocationPredictor: embed -> biLSTM -> attention x3 -> masked conv x2 -> loss
// B=128 T=256 E=512 HSZ=1024 HD=512 VOCAB=2048 LVOCAB=11 K=6 STEPS=3
// Output d_out = 2 x float32 (loss, acc). Workspace ~94 MB.
// Cooperative kernel (256 blocks, 1/CU): l0 sums -> biLSTM scan (emb16 gather,
// MALL h-exchange, 16-wide flags, tail pipeline) -> barrier -> conv1 -> conv2.
// Attention: single-pass online-softmax (flash-style), uint4 loads.
// ---------------------------------------------------------------------------

typedef _Float16 f16;
typedef __attribute__((ext_vector_type(8))) _Float16 f16x8;
typedef __attribute__((ext_vector_type(4))) float f32x4;

#define DEV __device__ __forceinline__

DEV void gload_lds16(const void* g, void* lds) {   // cached (L1+L2)
  __builtin_amdgcn_global_load_lds(
      (const __attribute__((address_space(1))) unsigned*)g,
      (__attribute__((address_space(3))) unsigned*)lds, 16, 0, 0);
}
DEV void gload_lds16c(const void* g, void* lds) {  // SC0|SC1: read MALL
  __builtin_amdgcn_global_load_lds(
      (const __attribute__((address_space(1))) unsigned*)g,
      (__attribute__((address_space(3))) unsigned*)lds, 16, 0, 17);
}
DEV float sigm(float x) { return 1.0f / (1.0f + __expf(-x)); }
DEV float tanh_(float x) { return 1.0f - 2.0f / (__expf(2.0f * x) + 1.0f); }
DEV unsigned pck(float a, float b) {
  union { unsigned u; f16 h[2]; } c; c.h[0] = (f16)a; c.h[1] = (f16)b; return c.u;
}

// ---------------------------------------------------------------------------
// Generic f16 GEMM (controller updates): C[M][N] = A[M][K]*B[N][K]^T (+bias).
// ---------------------------------------------------------------------------
__global__ __launch_bounds__(256) void gemm_kernel(
    const f16* __restrict__ A, const f16* __restrict__ B,
    const float* __restrict__ bias, void* __restrict__ Cp,
    int M, int N, int K, int cmode) {
  __shared__ f16 As[128 * 32];
  __shared__ f16 Bs[128 * 32];
  const int tid = threadIdx.x;
  const int w = tid >> 6, l = tid & 63;
  const int m0 = blockIdx.x * 128, n0 = blockIdx.y * 128;
  const int wm = (w & 1) * 64, wn = (w >> 1) * 64;
  const int lr = l & 15, lq = l >> 4;
  const int srow = w * 32 + (l >> 2);
  const int kc8 = (l & 3) * 8;
  f32x4 acc[4][4];
#pragma unroll
  for (int i = 0; i < 4; ++i)
#pragma unroll
    for (int j = 0; j < 4; ++j) acc[i][j] = (f32x4){0.f, 0.f, 0.f, 0.f};

  for (int kt = 0; kt < K; kt += 32) {
    __syncthreads();
#pragma unroll
    for (int i = 0; i < 2; ++i) {
      gload_lds16(A + (long)(m0 + srow + i * 16) * K + kt + kc8,
                  &As[(w * 32 + i * 16) * 32]);
      gload_lds16(B + (long)(n0 + srow + i * 16) * K + kt + kc8,
                  &Bs[(w * 32 + i * 16) * 32]);
    }
    __syncthreads();
    f16x8 af[4], bf[4];
#pragma unroll
    for (int mi = 0; mi < 4; ++mi)
      af[mi] = *(const f16x8*)&As[(wm + mi * 16 + lr) * 32 + lq * 8];
#pragma unroll
    for (int ni = 0; ni < 4; ++ni)
      bf[ni] = *(const f16x8*)&Bs[(wn + ni * 16 + lr) * 32 + lq * 8];
#pragma unroll
    for (int mi = 0; mi < 4; ++mi)
#pragma unroll
      for (int ni = 0; ni < 4; ++ni)
        acc[mi][ni] =
            __builtin_amdgcn_mfma_f32_16x16x32_f16(af[mi], bf[ni], acc[mi][ni], 0, 0, 0);
  }
#pragma unroll
  for (int mi = 0; mi < 4; ++mi)
#pragma unroll
    for (int ni = 0; ni < 4; ++ni)
#pragma unroll
      for (int r = 0; r < 4; ++r) {
        const int m = m0 + wm + mi * 16 + lq * 4 + r;  // C row = quad*4+reg
        const int n = n0 + wn + ni * 16 + lr;          // C col = lane&15
        float v = acc[mi][ni][r];
        if (bias) v += bias[n];
        if (cmode) ((f16*)Cp)[(long)m * N + n] = (f16)v;
        else       ((float*)Cp)[(long)m * N + n] = v;
      }
}

// full-grid (256 blocks) barrier: release fence -> counter -> acquire fence
DEV void grid_barrier(int* cnt, int* gen, int tid) {
  __syncthreads();
  if (tid == 0) {
    __threadfence();  // release: my block's stores -> device-visible
    const int a = __hip_atomic_fetch_add(cnt, 1, __ATOMIC_ACQ_REL,
                                         __HIP_MEMORY_SCOPE_SYSTEM);
    if (a == 255) {
      __hip_atomic_store(gen, 1, __ATOMIC_RELEASE, __HIP_MEMORY_SCOPE_SYSTEM);
    } else {
      while (__hip_atomic_load(gen, __ATOMIC_RELAXED,
                               __HIP_MEMORY_SCOPE_SYSTEM) == 0)
        __builtin_amdgcn_s_sleep(8);
    }
    __threadfence();  // acquire: invalidate before reading peers' data
  }
  __syncthreads();
}

// conv 64x128 tile: ldst[m0..+64][n0..+128] = patchgather(lsrc) @ w416^T.
DEV void conv_tile64(char* smem, int tid, const f16* lsrc, const f16* wsrc,
                     f16* ldst, int m0, int n0, const f16* zbuf) {
  f16* const As = (f16*)smem;             // 64 x 32 f16 = 4 KB
  f16* const Bs = (f16*)(smem + 4096);    // 128 x 32 f16 = 8 KB
  const int w = tid >> 6, l = tid & 63;
  const int wn = w * 32;
  const int lr = l & 15, lq = l >> 4;
  const int kc8 = (l & 3) * 8;
  f32x4 acc[4][2];
#pragma unroll
  for (int i = 0; i < 4; ++i)
#pragma unroll
    for (int j = 0; j < 2; ++j) acc[i][j] = (f32x4){0.f, 0.f, 0.f, 0.f};

  for (int kt = 0; kt < 4096; kt += 32) {
    __syncthreads();
    const int tap = kt >> 10;                  // wave-uniform
    const int ic = (kt & 1023) + kc8;          // per-lane k within tap
    {  // A: one instr per wave, rows m0 + w*16 + (l>>2)
      const int m = m0 + w * 16 + (l >> 2);
      const int b = m >> 4, p = m & 15, py = p >> 2, px = p & 3;
      const int nb = p + ((tap == 0) ? -4 : (tap == 1) ? -1 : (tap == 2) ? 1 : 4);
      const bool ok = (tap == 0) ? (py > 0) : (tap == 1) ? (px > 0)
                      : (tap == 2) ? (px < 3) : (py < 3);
      const f16* sa = ok ? (lsrc + ((long)(b * 16 + nb) * 1024 + ic)) : zbuf;
      gload_lds16(sa, &As[(w * 16) * 32]);
    }
#pragma unroll
    for (int i = 0; i < 2; ++i) {  // B: rows n0 + w*32 + i*16 + (l>>2)
      gload_lds16(wsrc + (long)(n0 + w * 32 + i * 16 + (l >> 2)) * 4096 + kt + kc8,
                  &Bs[(w * 32 + i * 16) * 32]);
    }
    __syncthreads();
    f16x8 af[4], bf[2];
#pragma unroll
    for (int mi = 0; mi < 4; ++mi)
      af[mi] = *(const f16x8*)&As[(mi * 16 + lr) * 32 + lq * 8];
#pragma unroll
    for (int ni = 0; ni < 2; ++ni)
      bf[ni] = *(const f16x8*)&Bs[(wn + ni * 16 + lr) * 32 + lq * 8];
#pragma unroll
    for (int mi = 0; mi < 4; ++mi)
#pragma unroll
      for (int ni = 0; ni < 2; ++ni)
        acc[mi][ni] =
            __builtin_amdgcn_mfma_f32_16x16x32_f16(af[mi], bf[ni], acc[mi][ni], 0, 0, 0);
  }
#pragma unroll
  for (int mi = 0; mi < 4; ++mi)
#pragma unroll
    for (int ni = 0; ni < 2; ++ni)
#pragma unroll
      for (int r = 0; r < 4; ++r) {
        const int m = m0 + mi * 16 + lq * 4 + r;
        const int n = n0 + wn + ni * 16 + lr;
        ldst[(long)m * 1024 + n] = (f16)acc[mi][ni][r];
      }
}

// ---------------------------------------------------------------------------
// Cooperative kernel: 256 blocks x 256 threads (1 block/CU, full VGPRs).
// ---------------------------------------------------------------------------
__global__ __launch_bounds__(256, 1) void lstm_conv_kernel(
    const int* __restrict__ Xs, const f16* __restrict__ emb16,
    const float* __restrict__ Wih_f, const float* __restrict__ Wih_b,
    const float* __restrict__ Whh_f, const float* __restrict__ Whh_b,
    const float* __restrict__ b_f, const float* __restrict__ b_b,
    f16* __restrict__ hg, f16* __restrict__ hidden, int* __restrict__ bar,
    const int* __restrict__ lm, const float* __restrict__ mapemb,
    f16* __restrict__ l0b, f16* __restrict__ l1b, f16* __restrict__ l2b,
    const f16* __restrict__ w416, const f16* __restrict__ zbuf) {
  __shared__ char smem[57344];
  const int blk = blockIdx.x, tid = threadIdx.x;
  const int w = tid >> 6, l = tid & 63;

  // ---- phase 0: l0b[bp][h] = sum_k mapemb[lm[bp][k]][h] (8 bp per block) ---
  for (int j = 0; j < 8; ++j) {
    const int bp = blk * 8 + j;
    const int h = tid * 4;
    float a0 = 0.f, a1 = 0.f, a2 = 0.f, a3 = 0.f;
#pragma unroll
    for (int k = 0; k < 6; ++k) {
      const float* r = mapemb + lm[bp * 6 + k] * 1024 + h;
      a0 += r[0]; a1 += r[1]; a2 += r[2]; a3 += r[3];
    }
    union { uint2 u; f16 hh[4]; } pk;
    pk.hh[0] = (f16)a0; pk.hh[1] = (f16)a1; pk.hh[2] = (f16)a2; pk.hh[3] = (f16)a3;
    *(uint2*)&l0b[(long)bp * 1024 + h] = pk.u;
  }

  // ========================== phase 1: biLSTM scan =========================
  f16* const hs = (f16*)smem;                 // 16 KB h stage [kt][m16][kk32]
  f16* const xs0 = (f16*)(smem + 16384);      // 16 KB x ping
  f16* const xs1 = (f16*)(smem + 32768);      // 16 KB x pong
  float* const gbp = (float*)(smem + 49152);  // 8 KB gate transpose
  const int d = blk >> 7, rr = blk & 127;
  const int ug = rr & 15, bg = rr >> 4;
  const int b0 = bg * 16;
  const int lr = l & 15, lq = l >> 4;
  const int u0 = ug * 32 + w * 8;             // wave-owned unit base
  const float* const Wih = d ? Wih_b : Wih_f;
  const float* const Whh = d ? Whh_b : Whh_f;
  const float* const bb = d ? b_b : b_f;
  int* const flagbase = &bar[((d << 3) + bg) << 4];

  // one-time: weights -> registers as MFMA B-fragments (f32 -> f16)
  f16x8 wih[16][2], whh[16][2];
#pragma unroll
  for (int kt = 0; kt < 16; ++kt)
#pragma unroll
    for (int nt = 0; nt < 2; ++nt) {
      const int n = nt * 16 + lr;                       // gate row within 32
      const long row = (long)((n >> 3) * 512 + u0 + (n & 7));
      const float* pi = Wih + row * 512 + kt * 32 + lq * 8;
      const float* ph = Whh + row * 512 + kt * 32 + lq * 8;
      f16x8 va, vb;
#pragma unroll
      for (int j = 0; j < 8; ++j) { va[j] = (f16)pi[j]; vb[j] = (f16)ph[j]; }
      wih[kt][nt] = va; whh[kt][nt] = vb;
    }
  const int bl = l >> 2, jp = (l & 3) * 2;   // eltwise: row bl, units jp,jp+1
  const int b_my = b0 + bl;
  const float bi0 = bb[u0 + jp],        bi1 = bb[u0 + jp + 1];
  const float bF0 = bb[512 + u0 + jp],  bF1 = bb[512 + u0 + jp + 1];
  const float bg0 = bb[1024 + u0 + jp], bg1 = bb[1024 + u0 + jp + 1];
  const float bo0 = bb[1536 + u0 + jp], bo1 = bb[1536 + u0 + jp + 1];
  float c0 = 0.f, c1 = 0.f;
  f16* const hbase = hg + (d * 2) * 65536;

#define STAGEH(SRCP)                                                          \
  {                                                                           \
    const f16* _s = (SRCP);                                                   \
    _Pragma("unroll") for (int k4 = 0; k4 < 4; ++k4) {                        \
      const int kt = w * 4 + k4;                                              \
      gload_lds16c(_s + (long)(l >> 2) * 512 + kt * 32 + (l & 3) * 8,         \
                   &hs[(kt * 16) * 32]);                                      \
    }                                                                         \
  }
#define STAGEX(DSTP, TP)                                                      \
  {                                                                           \
    const int _xr = Xs[(b0 + (l >> 2)) * 256 + (TP)];                         \
    const f16* _s = emb16 + (long)_xr * 512 + (l & 3) * 8;                    \
    _Pragma("unroll") for (int k4 = 0; k4 < 4; ++k4) {                        \
      const int kt = w * 4 + k4;                                              \
      gload_lds16(_s + kt * 32, &(DSTP)[(kt * 16) * 32]);                     \
    }                                                                         \
  }

  // pre-loop: stage x@t0 -> xs0; x-MFMA@t0; prefetch x@t1 -> xs1
  STAGEX(xs0, d ? 255 : 0);
  __builtin_amdgcn_s_waitcnt(0x0F70);  // vmcnt(0)
  __syncthreads();
  f32x4 a0 = (f32x4){0.f, 0.f, 0.f, 0.f}, a1 = (f32x4){0.f, 0.f, 0.f, 0.f};
#pragma unroll
  for (int kt = 0; kt < 16; ++kt) {
    const f16x8 av = *(const f16x8*)&xs0[(kt * 16 + lr) * 32 + lq * 8];
    a0 = __builtin_amdgcn_mfma_f32_16x16x32_f16(av, wih[kt][0], a0, 0, 0, 0);
    a1 = __builtin_amdgcn_mfma_f32_16x16x32_f16(av, wih[kt][1], a1, 0, 0, 0);
  }
  STAGEX(xs1, d ? 254 : 1);

  for (int s = 0; s < 256; ++s) {
    const int t = d ? (255 - s) : s;
    const f16* const hrd = hbase + (s & 1) * 65536;
    f16* const hwr = hbase + ((s + 1) & 1) * 65536;
    // 1. wait for h@s from the 16 writer blocks of my (d,bg)
    if (w == 0 && l < 16) {
      while (__hip_atomic_load(&flagbase[l], __ATOMIC_RELAXED,
                               __HIP_MEMORY_SCOPE_SYSTEM) < s)
        __builtin_amdgcn_s_sleep(1);
    }
    __syncthreads();
    // 2. stage h@s (coherent, from MALL)
    STAGEH(hrd + (long)b0 * 512);
    __builtin_amdgcn_s_waitcnt(0x0F70);  // vmcnt(0): hs + last x prefetch
    __syncthreads();                     // all waves' chunks landed
    // 3. h-MFMA on top of the x contribution computed in the previous tail
#pragma unroll
    for (int kt = 0; kt < 16; ++kt) {
      const f16x8 av = *(const f16x8*)&hs[(kt * 16 + lr) * 32 + lq * 8];
      a0 = __builtin_amdgcn_mfma_f32_16x16x32_f16(av, whh[kt][0], a0, 0, 0, 0);
      a1 = __builtin_amdgcn_mfma_f32_16x16x32_f16(av, whh[kt][1], a1, 0, 0, 0);
    }
    // 4. wave-local gate transpose + eltwise
#pragma unroll
    for (int r = 0; r < 4; ++r) {
      gbp[(w * 16 + lq * 4 + r) * 32 + lr] = a0[r];
      gbp[(w * 16 + lq * 4 + r) * 32 + 16 + lr] = a1[r];
    }
    __builtin_amdgcn_s_waitcnt(0xC07F);  // lgkmcnt(0): my LDS writes visible
    unsigned hp;
    {
      const float* const gr = &gbp[(w * 16 + bl) * 32];
      float gi = gr[jp] + bi0, gf = gr[8 + jp] + bF0;
      float gg = gr[16 + jp] + bg0, go = gr[24 + jp] + bo0;
      c0 = sigm(gf) * c0 + sigm(gi) * tanh_(gg);
      const float h0 = sigm(go) * tanh_(c0);
      gi = gr[jp + 1] + bi1; gf = gr[8 + jp + 1] + bF1;
      gg = gr[16 + jp + 1] + bg1; go = gr[24 + jp + 1] + bo1;
      c1 = sigm(gf) * c1 + sigm(gi) * tanh_(gg);
      const float h1 = sigm(go) * tanh_(c1);
      hp = pck(h0, h1);
      __hip_atomic_store((unsigned*)&hwr[(b_my << 9) + u0 + jp], hp,
                         __ATOMIC_RELAXED, __HIP_MEMORY_SCOPE_SYSTEM);
    }
    // 5. drain h stores, block-complete, publish flag
    __builtin_amdgcn_s_waitcnt(0x0F70);  // vmcnt(0)
    __syncthreads();
    if (tid == 0)
      __hip_atomic_store(&flagbase[ug], s + 1, __ATOMIC_RELAXED,
                         __HIP_MEMORY_SCOPE_SYSTEM);
    // 6. tail (hidden store, next x-MFMA, next prefetch) behind the publish
    *(unsigned*)&hidden[((long)b_my * 256 + t) * 1024 + (d << 9) + u0 + jp] = hp;
    if (s < 255) {
      a0 = (f32x4){0.f, 0.f, 0.f, 0.f}; a1 = (f32x4){0.f, 0.f, 0.f, 0.f};
      const f16* const xr = ((s + 1) & 1) ? xs1 : xs0;
#pragma unroll
      for (int kt = 0; kt < 16; ++kt) {
        const f16x8 av = *(const f16x8*)&xr[(kt * 16 + lr) * 32 + lq * 8];
        a0 = __builtin_amdgcn_mfma_f32_16x16x32_f16(av, wih[kt][0], a0, 0, 0, 0);
        a1 = __builtin_amdgcn_mfma_f32_16x16x32_f16(av, wih[kt][1], a1, 0, 0, 0);
      }
      if (s < 254) {
        f16* const xd = (s & 1) ? xs1 : xs0;
        STAGEX(xd, d ? (253 - s) : (s + 2));
      }
    }
  }
#undef STAGEH
#undef STAGEX

  // ================== phase 2: landmark conv (after scan) ==================
  const int m0 = (blk >> 3) * 64, n0 = (blk & 7) * 128;
  grid_barrier(&bar[512], &bar[528], tid);
  conv_tile64(smem, tid, l0b, w416, l1b, m0, n0, zbuf);
  grid_barrier(&bar[544], &bar[560], tid);
  conv_tile64(smem, tid, l1b, w416, l2b, m0, n0, zbuf);
}

// ---------------------------------------------------------------------------
// Attention (single pass, online softmax): wave w owns t in [w*64, w*64+64);
// lane l owns h-slice [l*16, l*16+16). Cross-wave combine via LDS.
// Writes msg (f32) and optionally cat=[msg||ctrl] f16.
// ---------------------------------------------------------------------------
__global__ __launch_bounds__(256) void att_kernel(
    const f16* __restrict__ hidden, const float* __restrict__ ctrl,
    const float* __restrict__ seq_mask, float* __restrict__ msg_out,
    f16* __restrict__ cat) {
  __shared__ float ctl[1024];
  __shared__ float wacc[4][1024];
  __shared__ float wml[4][2];
  const int b = blockIdx.x, tid = threadIdx.x;
  const int w = tid >> 6, l = tid & 63;
  for (int i = tid; i < 1024; i += 256) ctl[i] = ctrl[b * 1024 + i];
  __syncthreads();
  float cl[16];
#pragma unroll
  for (int j = 0; j < 16; ++j) cl[j] = ctl[l * 16 + j];
  const f16* hb = hidden + (long)b * 262144;
  float m = -1e38f, lsum = 0.f;
  float acc[16];
#pragma unroll
  for (int j = 0; j < 16; ++j) acc[j] = 0.f;
  for (int ti = 0; ti < 64; ++ti) {
    const int t = w * 64 + ti;
    union { uint4 u; f16 h[8]; } q0, q1;
    q0.u = *(const uint4*)&hb[t * 1024 + l * 16];
    q1.u = *(const uint4*)&hb[t * 1024 + l * 16 + 8];
    float hv[16];
#pragma unroll
    for (int j = 0; j < 8; ++j) { hv[j] = (float)q0.h[j]; hv[8 + j] = (float)q1.h[j]; }
    float s = 0.f;
#pragma unroll
    for (int j = 0; j < 16; ++j) s += hv[j] * cl[j];
#pragma unroll
    for (int off = 32; off; off >>= 1) s += __shfl_xor(s, off);
    s -= 1e30f * (1.0f - seq_mask[b * 256 + t]);
    const float mn = fmaxf(m, s);
    const float scale = __expf(m - mn);   // first iter: exp(-inf) = 0
    const float e = __expf(s - mn);
    lsum = lsum * scale + e;
#pragma unroll
    for (int j = 0; j < 16; ++j) acc[j] = acc[j] * scale + e * hv[j];
    m = mn;
  }
#pragma unroll
  for (int j = 0; j < 16; ++j) wacc[w][l * 16 + j] = acc[j];
  if (l == 0) { wml[w][0] = m; wml[w][1] = lsum; }
  __syncthreads();
  const float M = fmaxf(fmaxf(wml[0][0], wml[1][0]), fmaxf(wml[2][0], wml[3][0]));
  const float e0 = __expf(wml[0][0] - M), e1 = __expf(wml[1][0] - M);
  const float e2 = __expf(wml[2][0] - M), e3 = __expf(wml[3][0] - M);
  const float L = wml[0][1] * e0 + wml[1][1] * e1 + wml[2][1] * e2 + wml[3][1] * e3;
  const float invL = 1.0f / L;
  const int hc = tid * 4;
  float mv[4];
#pragma unroll
  for (int j = 0; j < 4; ++j) {
    mv[j] = (wacc[0][hc + j] * e0 + wacc[1][hc + j] * e1 +
             wacc[2][hc + j] * e2 + wacc[3][hc + j] * e3) * invL;
    msg_out[b * 1024 + hc + j] = mv[j];
  }
  if (cat) {
    f16* cm = cat + (long)b * 2048 + hc;
    cm[0] = (f16)mv[0]; cm[1] = (f16)mv[1]; cm[2] = (f16)mv[2]; cm[3] = (f16)mv[3];
    f16* cc = cat + (long)b * 2048 + 1024 + hc;
    cc[0] = (f16)ctl[hc]; cc[1] = (f16)ctl[hc + 1];
    cc[2] = (f16)ctl[hc + 2]; cc[3] = (f16)ctl[hc + 3];
  }
}

// logits -> softmax -> log_softmax(prob) -> loss/acc (atomicAdd into la[2] f32)
__global__ __launch_bounds__(256) void logits_kernel(
    const f16* __restrict__ l0, const f16* __restrict__ l1, const f16* __restrict__ l2,
    const float* __restrict__ msgs, const int* __restrict__ ys, float* __restrict__ la) {
  __shared__ float lg[16];
  const int b = blockIdx.x, tid = threadIdx.x;
  const int p = tid >> 4, q = tid & 15;
  const float* m0 = msgs + b * 1024;
  const float* m1 = msgs + 131072 + b * 1024;
  const float* m2 = msgs + 262144 + b * 1024;
  const long row = (long)(b * 16 + p) * 1024;
  float part = 0.f;
  for (int i = 0; i < 64; ++i) {
    const int h = q + 16 * i;
    part += (float)l0[row + h] * m0[h] + (float)l1[row + h] * m1[h] +
            (float)l2[row + h] * m2[h];
  }
#pragma unroll
  for (int off = 8; off; off >>= 1) part += __shfl_xor(part, off, 16);
  if (q == 0) lg[p] = part;
  __syncthreads();
  if (tid == 0) {
    float mx = lg[0];
    for (int i = 1; i < 16; ++i) mx = fmaxf(mx, lg[i]);
    float pr[16]; float s = 0.f;
    for (int i = 0; i < 16; ++i) { pr[i] = __expf(lg[i] - mx); s += pr[i]; }
    for (int i = 0; i < 16; ++i) pr[i] /= s;
    float mx2 = pr[0];
    for (int i = 1; i < 16; ++i) mx2 = fmaxf(mx2, pr[i]);
    float s2 = 0.f;
    for (int i = 0; i < 16; ++i) s2 += __expf(pr[i] - mx2);
    const float lse = mx2 + __logf(s2);
    const int y = ys[b * 2] * 4 + ys[b * 2 + 1];
    const float logp = pr[y] - lse;
    int am = 0; float bv = pr[0];
    for (int i = 1; i < 16; ++i) if (pr[i] > bv) { bv = pr[i]; am = i; }
    atomicAdd(&la[0], -logp * (1.0f / 128.0f));
    atomicAdd(&la[1], (am == y) ? (1.0f / 128.0f) : 0.0f);
  }
}

// d_out is 2 x FLOAT32 (loss, acc)
__global__ void finalize_kernel(const float* __restrict__ la,
                                float* __restrict__ out) {
  if (threadIdx.x == 0) { out[0] = la[0]; out[1] = la[1]; }
}

// merged init + weight prep (conv_w read COALESCED, taps scatter-written):
// emb16 f16 [2048][512]; updW16 f16 [1024][2048]; w416 f16 [1024][4096]
// tap-major (taps rc 1,3,5,7); zbuf zero page; hgb/bar/la zeroed;
// ctrlA = broadcast(feat_ctrl).  grid covers 9,437,184 conv_w elements.
__global__ __launch_bounds__(256) void setup_kernel(
    const float* __restrict__ emb, const float* __restrict__ upd_W,
    const float* __restrict__ conv_w, const float* __restrict__ feat,
    f16* __restrict__ emb16, f16* __restrict__ updW16, f16* __restrict__ w416,
    f16* __restrict__ zbuf, f16* __restrict__ hg, int* __restrict__ bar,
    float* __restrict__ la, float* __restrict__ ctrlA) {
  const int idx = blockIdx.x * 256 + threadIdx.x;  // 0..9437183
  if (idx < 9437184) {
    const float v = conv_w[idx];
    const int o = idx / 9216, rem = idx % 9216, i = rem / 9, rc = rem % 9;
    if (rc & 1)  // rc in {1,3,5,7} -> tap (rc-1)/2
      w416[(long)o * 4096 + ((rc - 1) >> 1) * 1024 + i] = (f16)v;
  }
  if (idx < 1048576) emb16[idx] = (f16)emb[idx];
  if (idx < 2097152) updW16[idx] = (f16)upd_W[idx];
  if (idx < 131072) { ((unsigned*)hg)[idx] = 0u; ctrlA[idx] = feat[idx & 1023]; }
  if (idx < 1024) bar[idx] = 0;
  if (idx < 128) zbuf[idx] = (f16)0.f;
  if (idx < 2) la[idx] = 0.f;
}

__global__ void fail_kernel(float* out, int mb) {
  if (threadIdx.x == 0) { out[0] = 12344.0f; out[1] = (float)mb; }
}

// ---------------------------------------------------------------------------
extern "C" void kernel_launch(void* const* d_in, const int* in_sizes, int n_in,
                              void* d_out, int out_size, void* d_ws, size_t ws_size,
                              hipStream_t stream) {
  (void)in_sizes; (void)n_in; (void)out_size;
  const int*   Xs      = (const int*)d_in[0];
  const float* seqmask = (const float*)d_in[1];
  const int*   lm      = (const int*)d_in[2];
  const int*   ys      = (const int*)d_in[3];
  const float* emb     = (const float*)d_in[4];
  const float* W_ih_f  = (const float*)d_in[5];
  const float* W_hh_f  = (const float*)d_in[6];
  const float* b_f     = (const float*)d_in[7];
  const float* W_ih_b  = (const float*)d_in[8];
  const float* W_hh_b  = (const float*)d_in[9];
  const float* b_b     = (const float*)d_in[10];
  const float* feat    = (const float*)d_in[11];
  const float* upd_W   = (const float*)d_in[12];
  const float* upd_b   = (const float*)d_in[13];
  const float* mapemb  = (const float*)d_in[14];
  const float* conv_w  = (const float*)d_in[15];
  float* out = (float*)d_out;  // 2 x f32 (loss, acc)
  char* ws = (char*)d_ws;
  size_t off = 0;
  auto alloc = [&](size_t bytes) {
    void* p = ws + off; off += (bytes + 255) & ~(size_t)255; return p;
  };
  f16*   hid    = (f16*)alloc(67108864);   // hidden f16 [b][t][1024]
  f16*   emb16  = (f16*)alloc(2097152);    // emb f16 [2048][512]
  f16*   hgb    = (f16*)alloc(524288);     // h state [d][parity][128][512]
  int*   bar    = (int*)alloc(4096);       // lstm flags | grid-barrier cnt/gen
  float* la     = (float*)alloc(256);      // loss/acc f32 accum
  float* ctrlA  = (float*)alloc(524288);
  float* ctrlB  = (float*)alloc(524288);
  float* msgs   = (float*)alloc(1572864);  // 3 x [128][1024] f32
  f16*   cat    = (f16*)alloc(524288);     // [128][2048] f16
  f16*   l0b    = (f16*)alloc(4194304);    // [b*16+p][1024] f16
  f16*   l1b    = (f16*)alloc(4194304);
  f16*   l2b    = (f16*)alloc(4194304);
  f16*   w416   = (f16*)alloc(8388608);    // [1024][4096] f16 tap-major
  f16*   updW16 = (f16*)alloc(4194304);    // [1024][2048] f16
  f16*   zbuf   = (f16*)alloc(256);        // zero page for OOB conv taps
  if (ws_size < off) {                     // ~94 MB needed
    fail_kernel<<<1, 64, 0, stream>>>(out, (int)(off >> 20));
    return;
  }

  setup_kernel<<<36864, 256, 0, stream>>>(emb, upd_W, conv_w, feat, emb16,
                                          updW16, w416, zbuf, hgb, bar, la, ctrlA);
  {
    void* args[] = {(void*)&Xs, (void*)&emb16,
                    (void*)&W_ih_f, (void*)&W_ih_b,
                    (void*)&W_hh_f, (void*)&W_hh_b, (void*)&b_f, (void*)&b_b,
                    (void*)&hgb, (void*)&hid, (void*)&bar,
                    (void*)&lm, (void*)&mapemb,
                    (void*)&l0b, (void*)&l1b, (void*)&l2b,
                    (void*)&w416, (void*)&zbuf};
    hipLaunchCooperativeKernel((void*)lstm_conv_kernel, dim3(256), dim3(256),
                               args, 0, stream);
  }
  // attention x3 (controller ping-pong); ctrl' = cat @ upd_W^T + upd_b (f32)
  att_kernel<<<128, 256, 0, stream>>>(hid, ctrlA, seqmask, msgs, cat);
  gemm_kernel<<<dim3(1, 8), 256, 0, stream>>>(cat, updW16, upd_b, ctrlB,
                                              128, 1024, 2048, 0);
  att_kernel<<<128, 256, 0, stream>>>(hid, ctrlB, seqmask, msgs + 131072, cat);
  gemm_kernel<<<dim3(1, 8), 256, 0, stream>>>(cat, updW16, upd_b, ctrlA,
                                              128, 1024, 2048, 0);
  att_kernel<<<128, 256, 0, stream>>>(hid, ctrlA, seqmask, msgs + 262144, nullptr);
  logits_kernel<<<128, 256, 0, stream>>>(l0b, l1b, l2b, msgs, ys, la);
  finalize_kernel<<<1, 64, 0, stream>>>(la, out);
}